// Round 2
// baseline (307.829 us; speedup 1.0000x reference)
//
#include <hip/hip_runtime.h>

// Problem constants (from reference setup_inputs): B=4096, n=64, C=256, K=3, T=68
#define NB   64    // n (number of basis functions / coeff rows)
#define NC   256   // C (channels)
#define NT   68    // T (knot count = n + K + 1)
#define DEG  3     // spline degree

// One block per batch element b; one thread per channel c.
// Cubic B-spline support width = DEG+1 = 4, so only 4 coeff rows are read per b.
__global__ __launch_bounds__(256) void bspline_kernel(
    const float* __restrict__ coeff,   // [B, 64, 256]
    const float* __restrict__ knots,   // [B, 68]
    const float* __restrict__ x_in,    // [B, 1]
    float* __restrict__ out,           // [B, 256]
    int Btotal)
{
    const int b = blockIdx.x;
    if (b >= Btotal) return;
    const int c = threadIdx.x;

    __shared__ float t[NT];
    if (c < NT) t[c] = knots[(size_t)b * NT + c];
    __syncthreads();

    const float x = x_in[b];

    // Find the unique interval j with t[j] <= x < t[j+1].
    // (Empty/degenerate intervals cannot contain x, so j is unique or absent.)
    int j = -1;
    #pragma unroll
    for (int i = 0; i < NT - 1; ++i) {
        if (t[i] <= x && x < t[i + 1]) j = i;
    }

    float acc = 0.0f;
    if (j >= 0) {
        // Windowed Cox-de Boor: after level kk, N[m] = B_kk[j - kk + m], m = 0..kk.
        // Matches reference semantics exactly (where(d==0, 0, .../d) guards).
        float N[DEG + 1] = {1.0f, 0.0f, 0.0f, 0.0f};
        #pragma unroll
        for (int kk = 1; kk <= DEG; ++kk) {
            #pragma unroll
            for (int m = DEG; m >= 0; --m) {
                if (m > kk) continue;
                const int i = j - kk + m;                 // basis index at this level
                const float oldm1 = (m - 1 >= 0) ? N[m - 1] : 0.0f;  // B_{kk-1}[i]
                const float oldm  = (m <= kk - 1) ? N[m] : 0.0f;     // B_{kk-1}[i+1]
                // Knot reads; clamp purely for memory safety. For every window
                // position that feeds a USED output (final i in [0,63]) the raw
                // indices are provably within [0,67], so clamping never changes
                // a used value.
                auto tc = [&](int idx) {
                    idx = idx < 0 ? 0 : (idx > NT - 1 ? NT - 1 : idx);
                    return t[idx];
                };
                const float t_i   = tc(i);
                const float t_ik  = tc(i + kk);
                const float t_i1  = tc(i + 1);
                const float t_ik1 = tc(i + kk + 1);
                const float d1 = t_ik  - t_i;
                const float d2 = t_ik1 - t_i1;
                const float w1 = (d1 == 0.0f) ? 0.0f : (x - t_i)   / d1;
                const float w2 = (d2 == 0.0f) ? 0.0f : (t_ik1 - x) / d2;
                N[m] = w1 * oldm1 + w2 * oldm;
            }
        }

        // out[b,c] = sum over the <=4 nonzero basis entries.
        const float* crow = coeff + (size_t)b * NB * NC + c;
        #pragma unroll
        for (int m = 0; m <= DEG; ++m) {
            const int i = j - DEG + m;
            if (i >= 0 && i < NB) {
                acc = fmaf(N[m], crow[(size_t)i * NC], acc);
            }
        }
    }

    out[(size_t)b * NC + c] = acc;
}

extern "C" void kernel_launch(void* const* d_in, const int* in_sizes, int n_in,
                              void* d_out, int out_size, void* d_ws, size_t ws_size,
                              hipStream_t stream) {
    const float* coeff = (const float*)d_in[0];  // [B, 64, 256] fp32
    const float* knots = (const float*)d_in[1];  // [B, 68] fp32
    const float* x_in  = (const float*)d_in[2];  // [B, 1] fp32
    float* out = (float*)d_out;                  // [B, 256] fp32

    const int B = in_sizes[2];                   // 4096

    bspline_kernel<<<B, NC, 0, stream>>>(coeff, knots, x_in, out, B);
}

// Round 4
// 300.109 us; speedup vs baseline: 1.0257x; 1.0257x over previous
//
#include <hip/hip_runtime.h>

// Problem constants (from reference setup_inputs): B=4096, n=64, C=256, K=3, T=68
#define NB   64    // n (coeff rows / basis functions)
#define NC   256   // C (channels)
#define NT   68    // T (knots = n + K + 1)
#define DEG  3     // spline degree
#define BPB  4     // batches per block (one 64-lane wave per batch)

// Block = 256 threads = 4 waves; wave w handles batch b = blockIdx.x*4 + w.
// Each lane covers 4 channels via float4. Cubic support width = 4 rows.
__global__ __launch_bounds__(256) void bspline_kernel(
    const float* __restrict__ coeff,   // [B, 64, 256]
    const float* __restrict__ knots,   // [B, 68]
    const float* __restrict__ x_in,    // [B, 1]
    float* __restrict__ out,           // [B, 256]
    int Btotal)
{
    const int wave = threadIdx.x >> 6;
    const int lane = threadIdx.x & 63;
    const int b = blockIdx.x * BPB + wave;

    __shared__ float t_s[BPB][NT];
    if (b < Btotal) {
        t_s[wave][lane] = knots[(size_t)b * NT + lane];
        if (lane < NT - 64) t_s[wave][64 + lane] = knots[(size_t)b * NT + 64 + lane];
    }
    __syncthreads();
    if (b >= Btotal) return;   // wave-uniform exit

    const float* t = t_s[wave];
    const float x = x_in[b];

    // Parallel interval search: lane i checks interval i (t[i] <= x < t[i+1]).
    // Interval is unique (overlap would need t[i+1] <= x < t[i+1]).
    int j = -1;
    {
        const bool c1 = (t[lane] <= x) && (x < t[lane + 1]);   // intervals 0..63
        const unsigned long long m1 = __ballot(c1);
        if (m1) {
            j = __ffsll((long long)m1) - 1;
        } else {
            const bool c2 = (lane < NT - 1 - 64) && (t[64 + lane] <= x) && (x < t[65 + lane]);
            const unsigned long long m2 = __ballot(c2);
            if (m2) j = 64 + __ffsll((long long)m2) - 1;
        }
    }

    float4 acc = make_float4(0.f, 0.f, 0.f, 0.f);
    if (j >= 0) {
        // Windowed Cox-de Boor: after level kk, N[m] = B_kk[j - kk + m], m = 0..kk.
        // Matches reference where(d==0, 0, .../d) guards exactly.
        float N[DEG + 1] = {1.0f, 0.0f, 0.0f, 0.0f};
        #pragma unroll
        for (int kk = 1; kk <= DEG; ++kk) {
            #pragma unroll
            for (int m = DEG; m >= 0; --m) {
                if (m > kk) continue;
                const int i = j - kk + m;
                const float oldm1 = (m - 1 >= 0) ? N[m - 1] : 0.0f;  // B_{kk-1}[i]
                const float oldm  = (m <= kk - 1) ? N[m] : 0.0f;     // B_{kk-1}[i+1]
                // Clamp for memory safety only; every window slot feeding a
                // used output (final i in [0,63]) has raw indices in [0,67].
                auto tc = [&](int idx) {
                    idx = idx < 0 ? 0 : (idx > NT - 1 ? NT - 1 : idx);
                    return t[idx];
                };
                const float t_i   = tc(i);
                const float t_ik  = tc(i + kk);
                const float t_i1  = tc(i + 1);
                const float t_ik1 = tc(i + kk + 1);
                const float d1 = t_ik  - t_i;
                const float d2 = t_ik1 - t_i1;
                const float w1 = (d1 == 0.0f) ? 0.0f : (x - t_i)   / d1;
                const float w2 = (d2 == 0.0f) ? 0.0f : (t_ik1 - x) / d2;
                N[m] = w1 * oldm1 + w2 * oldm;
            }
        }

        // acc[c4] = sum_m N[m] * coeff[b, j-3+m, 4*lane + c4], float4-vectorized.
        const float* base = coeff + (size_t)b * NB * NC + 4 * lane;
        #pragma unroll
        for (int m = 0; m <= DEG; ++m) {
            const int i = j - DEG + m;
            if (i >= 0 && i < NB) {
                const float4 v = *(const float4*)(base + (size_t)i * NC);
                acc.x = fmaf(N[m], v.x, acc.x);
                acc.y = fmaf(N[m], v.y, acc.y);
                acc.z = fmaf(N[m], v.z, acc.z);
                acc.w = fmaf(N[m], v.w, acc.w);
            }
        }
    }

    *(float4*)(out + (size_t)b * NC + 4 * lane) = acc;
}

extern "C" void kernel_launch(void* const* d_in, const int* in_sizes, int n_in,
                              void* d_out, int out_size, void* d_ws, size_t ws_size,
                              hipStream_t stream) {
    const float* coeff = (const float*)d_in[0];  // [B, 64, 256] fp32
    const float* knots = (const float*)d_in[1];  // [B, 68] fp32
    const float* x_in  = (const float*)d_in[2];  // [B, 1] fp32
    float* out = (float*)d_out;                  // [B, 256] fp32

    const int B = in_sizes[2];                   // 4096

    const int grid = (B + BPB - 1) / BPB;        // 1024 blocks
    bspline_kernel<<<grid, 256, 0, stream>>>(coeff, knots, x_in, out, B);
}